// Round 1
// baseline (371.841 us; speedup 1.0000x reference)
//
#include <hip/hip_runtime.h>

typedef unsigned int u32;
typedef unsigned short u16;
typedef float f32x4 __attribute__((ext_vector_type(4)));
typedef __bf16 bf16x8 __attribute__((ext_vector_type(8)));

#define BATCH 128
#define NIN   1024
#define DIN   256
#define NC    16
#define DC    32
#define NCOL  512

__device__ __forceinline__ float bflo(u32 v){ return __uint_as_float(v << 16); }
__device__ __forceinline__ float bfhi(u32 v){ return __uint_as_float(v & 0xffff0000u); }
__device__ __forceinline__ u32 bfround(u32 ua){ return (ua + 0x7fffu + ((ua >> 16) & 1u)) >> 16; }
__device__ __forceinline__ u32 pack2(float a, float b){
    return (bfround(__float_as_uint(a)) & 0xffffu) | (bfround(__float_as_uint(b)) << 16);
}

// Swizzled address (bf16 units) into the 64x256 bf16 transpose tile.
// Conflict-free for: row-wise 8B writes, column u16 gathers (xbT), column sums.
__device__ __forceinline__ int lds_x(int r, int d){
    int sw = (d >> 2) ^ ((r & 7) << 1) ^ (((r >> 3) & 3) << 2);
    return r * 256 + (sw << 2) + (d & 3);
}

// K0: per (b, 64-row j-chunk): stage x fp32 -> bf16 LDS; emit
//   xbT: j-contiguous MFMA B-fragment order: uint4[((b*16+dt)*32+js)*64+lane],
//        lane(l15,q) = x[js*32+q*8 .. +7][dt*16+l15]  (8 consecutive j, fixed d)
//   s[b,d] += column sums (iter-0 path);  Wb = bf16(W) (blocks with jc8==0)
__global__ __launch_bounds__(256) void k_pre(const float* __restrict__ x, const float* __restrict__ W,
                                             uint4* __restrict__ xbT, float* __restrict__ s,
                                             uint2* __restrict__ Wb){
    __shared__ __align__(16) u16 xt[64 * 256];   // 32 KB
    const int t = threadIdx.x, jc8 = blockIdx.x, b = blockIdx.y;

    if (jc8 == 0){   // W -> bf16 once per launch (128 blocks cover 131072 floats)
        float4 w4 = ((const float4*)W)[b * 256 + t];
        Wb[b * 256 + t] = make_uint2(pack2(w4.x, w4.y), pack2(w4.z, w4.w));
    }
    {   // stage 64x256 fp32 -> swizzled bf16 LDS (coalesced float4 loads)
        const float4* xg = (const float4*)(x + ((size_t)b * NIN + jc8 * 64) * DIN);
        int d4 = t & 63;                          // this thread's float4 column
        #pragma unroll
        for (int m = 0; m < 16; m++){
            int r = (t >> 6) + 4 * m;
            float4 v = xg[r * 64 + d4];
            *(uint2*)&xt[lds_x(r, d4 * 4)] = make_uint2(pack2(v.x, v.y), pack2(v.z, v.w));
        }
    }
    __syncthreads();
    {   // column sums of this chunk -> s[b,d]
        float acc = 0.f;
        #pragma unroll
        for (int r = 0; r < 64; r++) acc += bflo((u32)xt[lds_x(r, t)]);
        atomicAdd(&s[b * DIN + t], acc);
    }
    // transpose gather -> xbT (8 uint4 per thread, coalesced stores)
    #pragma unroll
    for (int w = 0; w < 8; w++){
        int oid = t + 256 * w;                    // 0..2047
        int lane = oid & 63, js2 = (oid >> 6) & 1, dt = oid >> 7;
        int l15 = lane & 15, q = lane >> 4;
        int rb = js2 * 32 + q * 8, d = dt * 16 + l15;
        u32 r[4];
        #pragma unroll
        for (int p = 0; p < 4; p++){
            u32 lo = xt[lds_x(rb + 2 * p, d)];
            u32 hi = xt[lds_x(rb + 2 * p + 1, d)];
            r[p] = lo | (hi << 16);
        }
        xbT[(((size_t)b * 16 + dt) * 32 + (jc8 * 2 + js2)) * 64 + lane] = make_uint4(r[0], r[1], r[2], r[3]);
    }
}

// K1: per (b, 128-row j-chunk): bb = v.x^T (MFMA, x fp32 direct + in-reg cvt);
//     softmax over i; z_part = c.x (MFMA via xbT). No u_hat anywhere.
__global__ __launch_bounds__(256) void k_main(const float* __restrict__ x, const uint4* __restrict__ xbT,
                                              const u16* __restrict__ vb, float* __restrict__ zp){
    __shared__ float bbl[16][132];                // bb logits, padded
    __shared__ __align__(16) u16 cl[16][136];     // softmax c, bf16, 16B-aligned rows (272B pitch)
    const int t = threadIdx.x, jh = blockIdx.x, b = blockIdx.y;
    const int lane = t & 63, wv = t >> 6;
    const int l15 = lane & 15, q = lane >> 4;

    // v A-fragments: lane(l15,q) = vb[b][i=l15][ks*32+q*8 .. +7]  (all 8 K-slices in regs)
    uint4 vfrag[8];
    #pragma unroll
    for (int ks = 0; ks < 8; ks++)
        vfrag[ks] = *(const uint4*)&vb[((size_t)b * 16 + l15) * 256 + ks * 32 + q * 8];

    // phase A: bb[i, jloc] ; B-frag = x rows (d-contiguous fp32 -> bf16 in reg)
    #pragma unroll
    for (int u = 0; u < 2; u++){
        int jt = wv * 2 + u;                      // 8 j-tiles / 4 waves
        const float* xr = x + ((size_t)b * NIN + jh * 128 + jt * 16 + l15) * DIN + q * 8;
        float4 xa[8][2];
        #pragma unroll
        for (int ks = 0; ks < 8; ks++){
            xa[ks][0] = *(const float4*)(xr + ks * 32);
            xa[ks][1] = *(const float4*)(xr + ks * 32 + 4);
        }
        f32x4 acc = {0.f, 0.f, 0.f, 0.f};
        #pragma unroll
        for (int ks = 0; ks < 8; ks++){
            uint4 xw;
            xw.x = pack2(xa[ks][0].x, xa[ks][0].y);
            xw.y = pack2(xa[ks][0].z, xa[ks][0].w);
            xw.z = pack2(xa[ks][1].x, xa[ks][1].y);
            xw.w = pack2(xa[ks][1].z, xa[ks][1].w);
            acc = __builtin_amdgcn_mfma_f32_16x16x32_bf16(
                __builtin_bit_cast(bf16x8, vfrag[ks]), __builtin_bit_cast(bf16x8, xw), acc, 0, 0, 0);
        }
        #pragma unroll
        for (int r = 0; r < 4; r++) bbl[q * 4 + r][jt * 16 + l15] = acc[r];   // D: row=i, col=j
    }
    __syncthreads();

    // phase B: softmax over i per column j
    if (t < 128){
        float mx = -1e30f, e[16], sum = 0.f;
        #pragma unroll
        for (int i = 0; i < 16; i++) mx = fmaxf(mx, bbl[i][t]);
        #pragma unroll
        for (int i = 0; i < 16; i++){ e[i] = __expf(bbl[i][t] - mx); sum += e[i]; }
        float inv = 1.f / sum;
        #pragma unroll
        for (int i = 0; i < 16; i++) cl[i][t] = (u16)bfround(__float_as_uint(e[i] * inv));
    }
    __syncthreads();

    // phase C: z_part[i,d] = sum_{j in chunk} c[i,j] x[j,d] ; B-frag from xbT (j-contiguous)
    bf16x8 cfrag[4];
    #pragma unroll
    for (int ksj = 0; ksj < 4; ksj++)
        cfrag[ksj] = __builtin_bit_cast(bf16x8, *(const uint4*)&cl[l15][ksj * 32 + q * 8]);
    #pragma unroll
    for (int u = 0; u < 4; u++){
        int dt = wv * 4 + u;                      // 16 d-tiles / 4 waves
        f32x4 acc = {0.f, 0.f, 0.f, 0.f};
        #pragma unroll
        for (int ksj = 0; ksj < 4; ksj++){
            uint4 bw = xbT[(((size_t)b * 16 + dt) * 32 + jh * 4 + ksj) * 64 + lane];
            acc = __builtin_amdgcn_mfma_f32_16x16x32_bf16(
                cfrag[ksj], __builtin_bit_cast(bf16x8, bw), acc, 0, 0, 0);
        }
        float* zpb = zp + ((((size_t)jh * 128 + b) * 16) * 256) + dt * 16 + l15;
        #pragma unroll
        for (int r = 0; r < 4; r++) zpb[(size_t)(q * 4 + r) * 256] = acc[r];
    }
}

// K2: y[b,i,k] = sum_d z[i,d] W[d,32i+k]  (z = sum of 8 partials; mode0: z=s/16);
//     squash; then v[b,i,d] = sum_k o[i,k] W[d,32i+k] -> vb (skip when final).
__global__ __launch_bounds__(512) void k_tail(const float* __restrict__ s, const float* __restrict__ zp,
                                              const u16* __restrict__ Wb, u16* __restrict__ vb,
                                              float* __restrict__ out, int mode){
    __shared__ float zl[16][260];
    __shared__ __align__(16) float ol[512];
    const int b = blockIdx.x, t = threadIdx.x;
    const int i = t >> 5;
    float y = 0.f;
    if (mode == 0){
        if (t < 256) zl[0][t] = s[b * 256 + t] * (1.f / 16.f);
        __syncthreads();
        #pragma unroll 8
        for (int d = 0; d < 256; d++) y += zl[0][d] * bflo((u32)Wb[d * 512 + t]);
    } else {
        #pragma unroll
        for (int u0 = 0; u0 < 8; u0++){
            int idx = t + 512 * u0;               // (ii, dd) over 16x256
            int ii = idx >> 8, dd = idx & 255;
            float acc = 0.f;
            #pragma unroll
            for (int jh = 0; jh < 8; jh++)
                acc += zp[((((size_t)jh * 128 + b) * 16 + ii) * 256) + dd];
            zl[ii][dd] = acc;
        }
        __syncthreads();
        #pragma unroll 8
        for (int d = 0; d < 256; d++) y += zl[i][d] * bflo((u32)Wb[d * 512 + t]);
    }
    // squash (unit-norm over k within each i-group of 32 lanes)
    float s2 = y * y;
    s2 += __shfl_xor(s2, 1); s2 += __shfl_xor(s2, 2); s2 += __shfl_xor(s2, 4);
    s2 += __shfl_xor(s2, 8); s2 += __shfl_xor(s2, 16);
    float r = y / sqrtf(s2 + 1e-7f);
    if (mode == 2){ out[b * 512 + t] = r; return; }
    ol[t] = r;
    __syncthreads();
    // v-pass for next iteration's bb
    {
        int d = t & 255, ih = t >> 8;
        #pragma unroll
        for (int ii2 = 0; ii2 < 8; ii2++){
            int i2 = ih * 8 + ii2;
            const float4* op = (const float4*)&ol[i2 * 32];
            float acc = 0.f;
            #pragma unroll
            for (int w4 = 0; w4 < 4; w4++){
                uint4 wv4 = *(const uint4*)&Wb[(size_t)d * 512 + i2 * 32 + w4 * 8];
                float4 o0 = op[w4 * 2], o1 = op[w4 * 2 + 1];
                acc += o0.x * bflo(wv4.x) + o0.y * bfhi(wv4.x) + o0.z * bflo(wv4.y) + o0.w * bfhi(wv4.y)
                     + o1.x * bflo(wv4.z) + o1.y * bfhi(wv4.z) + o1.z * bflo(wv4.w) + o1.w * bfhi(wv4.w);
            }
            vb[((size_t)b * 16 + i2) * 256 + d] = (u16)bfround(__float_as_uint(acc));
        }
    }
}

extern "C" void kernel_launch(void* const* d_in, const int* in_sizes, int n_in,
                              void* d_out, int out_size, void* d_ws, size_t ws_size,
                              hipStream_t stream){
    const float* x = (const float*)d_in[0];    // fp32 [128][1024][256]
    const float* W = (const float*)d_in[1];    // fp32 [256][512]
    float* out = (float*)d_out;                // fp32 [128][16][32]
    char* ws = (char*)d_ws;                    // 81.4 MB used (was 135 MB)
    float* s    = (float*)(ws);                //   131,072 B : column sums
    u16*   vb   = (u16*)  (ws + 131072);       // 1,048,576 B : v = o.W-slices, bf16
    u16*   Wb   = (u16*)  (ws + 1179648);      //   262,144 B : W bf16
    float* zp   = (float*)(ws + 1441792);      // 16,777,216 B : z partials [8][128][16][256]
    uint4* xbT  = (uint4*)(ws + 18219008);     // 67,108,864 B : x bf16, j-contiguous frag order

    hipMemsetAsync(s, 0, 131072, stream);
    k_pre<<<dim3(16, BATCH), 256, 0, stream>>>(x, W, xbT, s, (uint2*)Wb);
    k_tail<<<BATCH, 512, 0, stream>>>(s, zp, Wb, vb, out, 0);
    for (int it = 1; it < 4; it++){
        k_main<<<dim3(8, BATCH), 256, 0, stream>>>(x, xbT, vb, zp);
        k_tail<<<BATCH, 512, 0, stream>>>(s, zp, Wb, vb, out, it == 3 ? 2 : 1);
    }
}

// Round 2
// 361.934 us; speedup vs baseline: 1.0274x; 1.0274x over previous
//
#include <hip/hip_runtime.h>

typedef unsigned int u32;
typedef unsigned short u16;
typedef float f32x4 __attribute__((ext_vector_type(4)));
typedef __bf16 bf16x8 __attribute__((ext_vector_type(8)));

#define BATCH 128
#define NIN   1024
#define DIN   256
#define NC    16
#define DC    32
#define NCOL  512

__device__ __forceinline__ float bflo(u32 v){ return __uint_as_float(v << 16); }
__device__ __forceinline__ float bfhi(u32 v){ return __uint_as_float(v & 0xffff0000u); }
__device__ __forceinline__ u32 bfround(u32 ua){ return (ua + 0x7fffu + ((ua >> 16) & 1u)) >> 16; }
__device__ __forceinline__ u32 pack2(float a, float b){
    return (bfround(__float_as_uint(a)) & 0xffffu) | (bfround(__float_as_uint(b)) << 16);
}
__device__ __forceinline__ bf16x8 ldfrag(const u16* p){
    return __builtin_bit_cast(bf16x8, *(const uint4*)p);
}

// Swizzled address (bf16 units) into the 64x256 bf16 transpose tile.
__device__ __forceinline__ int lds_x(int r, int d){
    int sw = (d >> 2) ^ ((r & 7) << 1) ^ (((r >> 3) & 3) << 2);
    return r * 256 + (sw << 2) + (d & 3);
}

// K0: per (b, 64-row j-chunk):
//   xb : row-major bf16 x [b][j][d]                (phase-A B-fragments)
//   xbT: j-contiguous MFMA B-fragment order        (phase-C B-fragments)
//   s  : += column sums (iter-0 path)
//   Wb : bf16 W [d][c]   WT : bf16 W^T [c][d]      (blocks with jc8==0)
__global__ __launch_bounds__(256) void k_pre(const float* __restrict__ x, const float* __restrict__ W,
                                             uint4* __restrict__ xbT, u16* __restrict__ xb,
                                             float* __restrict__ s, uint2* __restrict__ Wb,
                                             uint2* __restrict__ WT){
    __shared__ __align__(16) u16 xt[64 * 256];   // 32 KB
    const int t = threadIdx.x, jc8 = blockIdx.x, b = blockIdx.y;

    if (jc8 == 0){   // W conversions, 128 blocks cover all of W
        int id = b * 256 + t;                    // 0..32767
        float4 w4 = ((const float4*)W)[id];
        Wb[id] = make_uint2(pack2(w4.x, w4.y), pack2(w4.z, w4.w));
        int c = id >> 6, d4 = id & 63;           // WT[c][4*d4 .. +3]
        float e0 = W[(size_t)(d4 * 4 + 0) * NCOL + c];
        float e1 = W[(size_t)(d4 * 4 + 1) * NCOL + c];
        float e2 = W[(size_t)(d4 * 4 + 2) * NCOL + c];
        float e3 = W[(size_t)(d4 * 4 + 3) * NCOL + c];
        WT[c * 64 + d4] = make_uint2(pack2(e0, e1), pack2(e2, e3));
    }
    {   // stage 64x256 fp32 -> swizzled bf16 LDS + row-major bf16 to xb
        const float4* xg = (const float4*)(x + ((size_t)b * NIN + jc8 * 64) * DIN);
        uint2* xbw = (uint2*)xb + ((size_t)(b * NIN + jc8 * 64)) * 64;
        int d4 = t & 63;
        #pragma unroll
        for (int m = 0; m < 16; m++){
            int r = (t >> 6) + 4 * m;
            float4 v = xg[r * 64 + d4];
            uint2 p = make_uint2(pack2(v.x, v.y), pack2(v.z, v.w));
            *(uint2*)&xt[lds_x(r, d4 * 4)] = p;
            xbw[r * 64 + d4] = p;
        }
    }
    __syncthreads();
    {   // column sums of this chunk -> s[b,d]
        float acc = 0.f;
        #pragma unroll
        for (int r = 0; r < 64; r++) acc += bflo((u32)xt[lds_x(r, t)]);
        atomicAdd(&s[b * DIN + t], acc);
    }
    // transpose gather -> xbT (8 uint4 per thread, coalesced stores)
    #pragma unroll
    for (int w = 0; w < 8; w++){
        int oid = t + 256 * w;                    // 0..2047
        int lane = oid & 63, js2 = (oid >> 6) & 1, dt = oid >> 7;
        int l15 = lane & 15, q = lane >> 4;
        int rb = js2 * 32 + q * 8, d = dt * 16 + l15;
        u32 r[4];
        #pragma unroll
        for (int p = 0; p < 4; p++){
            u32 lo = xt[lds_x(rb + 2 * p, d)];
            u32 hi = xt[lds_x(rb + 2 * p + 1, d)];
            r[p] = lo | (hi << 16);
        }
        xbT[(((size_t)b * 16 + dt) * 32 + (jc8 * 2 + js2)) * 64 + lane] = make_uint4(r[0], r[1], r[2], r[3]);
    }
}

// K1: per (b, 128-row j-chunk): bb = v.x^T (MFMA, bf16 xb); softmax over i;
//     z_part = c.x (MFMA via xbT).
__global__ __launch_bounds__(256) void k_main(const u16* __restrict__ xb, const uint4* __restrict__ xbT,
                                              const u16* __restrict__ vb, float* __restrict__ zp){
    __shared__ float bbl[16][132];
    __shared__ __align__(16) u16 cl[16][136];
    const int t = threadIdx.x, jh = blockIdx.x, b = blockIdx.y;
    const int lane = t & 63, wv = t >> 6;
    const int l15 = lane & 15, q = lane >> 4;

    // v A-fragments: lane(l15,q) = vb[b][i=l15][ks*32+q*8 .. +7]
    uint4 vfrag[8];
    #pragma unroll
    for (int ks = 0; ks < 8; ks++)
        vfrag[ks] = *(const uint4*)&vb[((size_t)b * 16 + l15) * 256 + ks * 32 + q * 8];

    // phase A: bb[i, jloc]; B-frag straight from bf16 xb rows
    const u16* xrow = xb + ((size_t)(b * NIN + jh * 128)) * 256;
    #pragma unroll
    for (int u = 0; u < 2; u++){
        int jt = wv * 2 + u;
        const u16* xr = xrow + (jt * 16 + l15) * 256 + q * 8;
        f32x4 acc = {0.f, 0.f, 0.f, 0.f};
        #pragma unroll
        for (int ks = 0; ks < 8; ks++)
            acc = __builtin_amdgcn_mfma_f32_16x16x32_bf16(
                __builtin_bit_cast(bf16x8, vfrag[ks]), ldfrag(xr + ks * 32), acc, 0, 0, 0);
        #pragma unroll
        for (int r = 0; r < 4; r++) bbl[q * 4 + r][jt * 16 + l15] = acc[r];   // row=i, col=j
    }
    __syncthreads();

    // phase B: softmax over i per column j
    if (t < 128){
        float mx = -1e30f, e[16], sum = 0.f;
        #pragma unroll
        for (int i = 0; i < 16; i++) mx = fmaxf(mx, bbl[i][t]);
        #pragma unroll
        for (int i = 0; i < 16; i++){ e[i] = __expf(bbl[i][t] - mx); sum += e[i]; }
        float inv = 1.f / sum;
        #pragma unroll
        for (int i = 0; i < 16; i++) cl[i][t] = (u16)bfround(__float_as_uint(e[i] * inv));
    }
    __syncthreads();

    // phase C: z_part[i,d] = sum_{j in chunk} c[i,j] x[j,d]
    bf16x8 cfrag[4];
    #pragma unroll
    for (int ksj = 0; ksj < 4; ksj++)
        cfrag[ksj] = __builtin_bit_cast(bf16x8, *(const uint4*)&cl[l15][ksj * 32 + q * 8]);
    #pragma unroll
    for (int u = 0; u < 4; u++){
        int dt = wv * 4 + u;
        f32x4 acc = {0.f, 0.f, 0.f, 0.f};
        #pragma unroll
        for (int ksj = 0; ksj < 4; ksj++){
            uint4 bw = xbT[(((size_t)b * 16 + dt) * 32 + jh * 4 + ksj) * 64 + lane];
            acc = __builtin_amdgcn_mfma_f32_16x16x32_bf16(
                cfrag[ksj], __builtin_bit_cast(bf16x8, bw), acc, 0, 0, 0);
        }
        float* zpb = zp + ((((size_t)jh * 128 + b) * 16) * 256) + dt * 16 + l15;
        #pragma unroll
        for (int r = 0; r < 4; r++) zpb[(size_t)(q * 4 + r) * 256] = acc[r];
    }
}

// K2: per (b, half): 8 capsules. y = z.W (coalesced Wb), squash,
//     v = o.W via WT (d contiguous across threads, coalesced).
__global__ __launch_bounds__(256) void k_tail(const float* __restrict__ s, const float* __restrict__ zp,
                                              const u16* __restrict__ Wb, const u32* __restrict__ WT32,
                                              u16* __restrict__ vb, float* __restrict__ out, int mode){
    __shared__ float zl[8][260];
    __shared__ __align__(16) float ol[256];
    const int ih2 = blockIdx.x, b = blockIdx.y, t = threadIdx.x;
    const int i_loc = t >> 5;                     // 0..7
    const int o_idx = ih2 * 256 + t;              // global (i,k) flat index
    float y = 0.f;
    if (mode == 0){
        zl[0][t] = s[b * 256 + t] * (1.f / 16.f); // t<256 covers all d
        __syncthreads();
        #pragma unroll 8
        for (int d = 0; d < 256; d++) y += zl[0][d] * bflo((u32)Wb[d * 512 + o_idx]);
    } else {
        #pragma unroll
        for (int u0 = 0; u0 < 8; u0++){
            int idx = t + 256 * u0;               // (ii, dd) over 8x256
            int ii = idx >> 8, dd = idx & 255;
            int ig = ih2 * 8 + ii;
            float acc = 0.f;
            #pragma unroll
            for (int jh = 0; jh < 8; jh++)
                acc += zp[((((size_t)jh * 128 + b) * 16 + ig) * 256) + dd];
            zl[ii][dd] = acc;
        }
        __syncthreads();
        #pragma unroll 8
        for (int d = 0; d < 256; d++) y += zl[i_loc][d] * bflo((u32)Wb[d * 512 + o_idx]);
    }
    // squash (unit-norm over the 32 k-lanes of each capsule)
    float s2 = y * y;
    s2 += __shfl_xor(s2, 1); s2 += __shfl_xor(s2, 2); s2 += __shfl_xor(s2, 4);
    s2 += __shfl_xor(s2, 8); s2 += __shfl_xor(s2, 16);
    float r = y / sqrtf(s2 + 1e-7f);
    if (mode == 2){ out[b * 512 + o_idx] = r; return; }
    ol[t] = r;
    __syncthreads();
    // v-pass: thread owns d-pair d0=2*dh; 4 capsules from its half
    {
        int dh = t & 127, ihalf = t >> 7;
        #pragma unroll
        for (int e = 0; e < 4; e++){
            int ii = ihalf * 4 + e;
            int i2 = ih2 * 8 + ii;
            float a0 = 0.f, a1 = 0.f;
            #pragma unroll
            for (int k = 0; k < 32; k++){
                u32 wv2 = WT32[(size_t)(i2 * 32 + k) * 128 + dh];
                float ok = ol[ii * 32 + k];
                a0 += ok * bflo(wv2); a1 += ok * bfhi(wv2);
            }
            ((u32*)vb)[(size_t)(b * 16 + i2) * 128 + dh] = pack2(a0, a1);
        }
    }
}

extern "C" void kernel_launch(void* const* d_in, const int* in_sizes, int n_in,
                              void* d_out, int out_size, void* d_ws, size_t ws_size,
                              hipStream_t stream){
    const float* x = (const float*)d_in[0];    // fp32 [128][1024][256]
    const float* W = (const float*)d_in[1];    // fp32 [256][512]
    float* out = (float*)d_out;                // fp32 [128][16][32]
    char* ws = (char*)d_ws;
    float* s    = (float*)(ws);                //   131,072 B : column sums
    u16*   vb   = (u16*)  (ws + 131072);       // 1,048,576 B : v = o.W-slices, bf16
    u16*   Wb   = (u16*)  (ws + 1179648);      //   262,144 B : W bf16 [d][c]
    u32*   WT   = (u32*)  (ws + 1441792);      //   262,144 B : W^T bf16 [c][d]
    float* zp   = (float*)(ws + 1703936);      // 16,777,216 B : z partials [8][128][16][256]
    u16*   xb   = (u16*)  (ws + 18481152);     // 67,108,864 B : x bf16 row-major
    uint4* xbT  = (uint4*)(ws + 85590016);     // 67,108,864 B : x bf16 j-contiguous frag order

    hipMemsetAsync(s, 0, 131072, stream);
    k_pre<<<dim3(16, BATCH), 256, 0, stream>>>(x, W, xbT, xb, s, (uint2*)Wb, (uint2*)WT);
    k_tail<<<dim3(2, BATCH), 256, 0, stream>>>(s, zp, Wb, WT, vb, out, 0);
    for (int it = 1; it < 4; it++){
        k_main<<<dim3(8, BATCH), 256, 0, stream>>>(xb, xbT, vb, zp);
        k_tail<<<dim3(2, BATCH), 256, 0, stream>>>(s, zp, Wb, WT, vb, out, it == 3 ? 2 : 1);
    }
}